// Round 13
// baseline (50.966 us; speedup 1.0000x reference)
//
#include <hip/hip_runtime.h>

#define CIN   32
#define COUT  64
#define HH    64
#define WW    64
#define NB    4
#define TH    8              // rows per block
#define CPT   2              // output channels per thread
#define XPR   66             // padded rows: image row r at xp row r+1
#define XPC   68             // padded col stride: image col c at xp col c+1 (+2 slack for x4 reads)
// xp[n][ci][XPR][XPC] in d_ws: zero-padded x. Tap read = one unaligned dwordx4 per window row.
// packed weight LDS: sw[ci][36] = [A(co0) 9 | A(co1) 9 | C(co0) 9 | C(co1) 9]

__global__ __launch_bounds__(256)
void pad_x(const float* __restrict__ x, float* __restrict__ xp)
{
    int idx = blockIdx.x * 256 + threadIdx.x;
    if (idx >= NB * CIN * XPR * XPC) return;
    int c  = idx % XPC;
    int t  = idx / XPC;
    int r  = t % XPR;
    int nc = t / XPR;                       // n*CIN + ci
    int gi = r - 1, gj = c - 1;
    float v = 0.0f;
    if ((unsigned)gi < (unsigned)HH && (unsigned)gj < (unsigned)WW)
        v = x[(size_t)nc * (HH * WW) + gi * WW + gj];
    xp[idx] = v;
}

template<int S>
__device__ __forceinline__ void math_all(const float* __restrict__ xl,  // lane base (ci=0, window row 0, col tl)
                                         const float* __restrict__ sw,
                                         float aeg[2][CPT], float cv[2][CPT])
{
    #pragma unroll 4
    for (int ci = 0; ci < CIN; ++ci) {
        const float* p = xl + ci * (XPR * XPC);
        // 5 window rows, one 16B read each: x=tl, y=tc, z=tr (w unused)
        float4 t[5];
        #pragma unroll
        for (int wr = 0; wr < 5; ++wr)
            __builtin_memcpy(&t[wr], p + wr * XPC, 16);

        // packed weights: 9 x ds_read_b128 broadcast
        float w[36];
        const float* pw = sw + ci * 36;
        #pragma unroll
        for (int u = 0; u < 9; ++u)
            *(float4*)&w[4 * u] = *(const float4*)&pw[4 * u];

        #pragma unroll
        for (int c = 0; c < CPT; ++c) {
            const float* wA = &w[c * 9];
            const float* wC = &w[18 + c * 9];
            #pragma unroll
            for (int pp = 0; pp < 2; ++pp) {
                float r = 0.0f;
                #pragma unroll
                for (int k = 0; k < 9; ++k) {
                    const int wr = 2 * pp + k / 3;
                    const int kj = k % 3;
                    const float tv = (kj == 0) ? t[wr].x : ((kj == 1) ? t[wr].y : t[wr].z);
                    const float prod = tv * wA[k];
                    // pixel parity == S -> step parity = S^(k&1); even: r=(r+t)*y, odd: r=(r+y)*t
                    r = ((k & 1) == S) ? fmaf(r, wA[k], prod) : fmaf(r, tv, prod);
                    cv[pp][c] = fmaf(tv, wC[k], cv[pp][c]);
                }
                aeg[pp][c] += r;
            }
        }
    }
}

__global__ __launch_bounds__(256, 4)
void aeg_conv_kernel(const float* __restrict__ xp,
                     const float* __restrict__ weight,
                     const float* __restrict__ conv_w,
                     const float* __restrict__ conv_b,
                     float* __restrict__ out)
{
    __shared__ float sw[CIN * 36];                // 4608 B only

    const int tid = threadIdx.x;
    const int i0  = blockIdx.x * TH;
    const int n   = blockIdx.y;
    const int co0 = blockIdx.z * CPT;

    const int s  = (tid >> 6) & 1;      // wave parity class (wave-uniform)
    const int rg = tid >> 7;            // row group (0,1)
    const int h  = (tid >> 5) & 1;      // half-wave -> row offset
    const int m  = tid & 31;

    const int rb_local = rg * 4 + h;            // local first pixel row: {0,1,4,5}; owns +0,+2
    const int rb  = i0 + rb_local;              // absolute first pixel row
    const int cb  = (rb & 1) ^ s;               // column LSB for this lane's class
    const int col = 2 * m + cb;                 // owned column (both pixel rows)

    // ---- stage packed weight slice into LDS: [ci][A0|A1|C0|C1] ----
    for (int idx = tid; idx < CIN * 36; idx += 256) {
        int ci = idx / 36, slot = idx - ci * 36;
        int set = slot / 18, rem = slot - set * 18;
        int c2 = rem / 9, k = rem - c2 * 9;
        const float* src = set ? conv_w : weight;
        sw[idx] = src[((size_t)(co0 + c2) * CIN + ci) * 9 + k];
    }
    __syncthreads();                    // the only barrier in the kernel

    // lane base: window row 0 = image row rb-1 = xp row rb; tl col = col-1 = xp col 'col'
    const float* xl = xp + ((size_t)(n * CIN) * XPR + rb) * XPC + col;

    float aeg[2][CPT], cv[2][CPT];
    #pragma unroll
    for (int p = 0; p < 2; ++p)
        #pragma unroll
        for (int c = 0; c < CPT; ++c) { aeg[p][c] = 0.0f; cv[p][c] = 0.0f; }

    if (s == 0) math_all<0>(xl, sw, aeg, cv);
    else        math_all<1>(xl, sw, aeg, cv);

    // ---- epilogue: sigmoid(aeg) * (conv + bias) ----
    #pragma unroll
    for (int p = 0; p < 2; ++p) {
        int i = rb + 2 * p;
        #pragma unroll
        for (int c = 0; c < CPT; ++c) {
            int co = co0 + c;
            float conv = cv[p][c] + conv_b[co];
            float sg = 1.0f / (1.0f + __expf(-aeg[p][c]));
            out[(((size_t)n * COUT + co) * HH + i) * WW + col] = sg * conv;
        }
    }
}

extern "C" void kernel_launch(void* const* d_in, const int* in_sizes, int n_in,
                              void* d_out, int out_size, void* d_ws, size_t ws_size,
                              hipStream_t stream) {
    const float* x      = (const float*)d_in[0];
    const float* weight = (const float*)d_in[1];
    const float* conv_w = (const float*)d_in[2];
    const float* conv_b = (const float*)d_in[3];
    float* out = (float*)d_out;
    float* xp  = (float*)d_ws;          // needs NB*CIN*XPR*XPC*4 = 2,297,856 B

    const int total = NB * CIN * XPR * XPC;
    pad_x<<<(total + 255) / 256, 256, 0, stream>>>(x, xp);

    dim3 grid(HH / TH, NB, COUT / CPT);   // 8 x 4 x 32 = 1024 blocks
    aeg_conv_kernel<<<grid, 256, 0, stream>>>(xp, weight, conv_w, conv_b, out);
}

// Round 14
// 33.500 us; speedup vs baseline: 1.5214x; 1.5214x over previous
//
#include <hip/hip_runtime.h>

#define CIN   32
#define COUT  64
#define HH    64
#define WW    64
#define NB    4
#define TH    8              // rows per block
#define HR    (TH + 2)       // 10 staged rows
#define G     8              // input channels per LDS round
#define CPT   2              // output channels per thread
#define ROWCI 72             // dwords per (row, ci): two 36-dword parity arrays
// parity array layout (36 dwords): [0]=left halo (col -1), [1..32]=cols, [33]=right halo (col 64)
// packed weight LDS: sw[ci][36] = [A(co0) 9 | A(co1) 9 | C(co0) 9 | C(co1) 9]

// ---- VOP3P packed-f32 helpers (CDNA4: v_pk_* = 2 fp32 ops/inst) ----
__device__ __forceinline__ float2 pk_fma_(float2 a, float2 b, float2 c) {   // a*b+c per half
    float2 d;
    asm("v_pk_fma_f32 %0, %1, %2, %3" : "=v"(d) : "v"(a), "v"(b), "v"(c));
    return d;
}
__device__ __forceinline__ float2 pk_add_(float2 a, float2 b) {
    float2 d;
    asm("v_pk_add_f32 %0, %1, %2" : "=v"(d) : "v"(a), "v"(b));
    return d;
}
template<int HI>        // a * {b[HI],b[HI]} : broadcast one half of pair b via op_sel
__device__ __forceinline__ float2 pk_mul_sel(float2 a, float2 b) {
    float2 d;
    if (HI) asm("v_pk_mul_f32 %0, %1, %2 op_sel:[0,1] op_sel_hi:[1,1]" : "=v"(d) : "v"(a), "v"(b));
    else    asm("v_pk_mul_f32 %0, %1, %2 op_sel:[0,0] op_sel_hi:[1,0]" : "=v"(d) : "v"(a), "v"(b));
    return d;
}
template<int HI>        // a * {b[HI],b[HI]} + c
__device__ __forceinline__ float2 pk_fma_sel(float2 a, float2 b, float2 c) {
    float2 d;
    if (HI) asm("v_pk_fma_f32 %0, %1, %2, %3 op_sel:[0,1,0] op_sel_hi:[1,1,1]" : "=v"(d) : "v"(a), "v"(b), "v"(c));
    else    asm("v_pk_fma_f32 %0, %1, %2, %3 op_sel:[0,0,0] op_sel_hi:[1,0,1]" : "=v"(d) : "v"(a), "v"(b), "v"(c));
    return d;
}

template<int S>
__device__ __forceinline__ void math_g(const float* __restrict__ sx,
                                       const float* __restrict__ sw,
                                       int lrow, int m, int cb, int g,
                                       float2 aeg2[CPT], float2 cv2[CPT])
{
    #pragma unroll 2
    for (int cl = 0; cl < G; ++cl) {
        const int ci = g + cl;
        // 15 taps: 5 window rows x (center b32 + side pair -> ds_read2_b32)
        float tc[5], tl[5], tr[5];
        #pragma unroll
        for (int wr = 0; wr < 5; ++wr) {
            const int qc = (wr & 1) ^ 1 ^ S;              // compile-time array select
            const float* rowp = sx + (lrow + wr) * (G * ROWCI) + cl * ROWCI;
            tc[wr] = rowp[qc * 36 + 1 + m];
            const float* sp = rowp + (1 - qc) * 36 + m + cb;
            tl[wr] = sp[0];
            tr[wr] = sp[1];
        }
        // pixel-pair taps: lo = p0 (window rows 0..2), hi = p1 (window rows 2..4)
        float2 t2c[3], t2l[3], t2r[3];
        #pragma unroll
        for (int wr = 0; wr < 3; ++wr) {
            t2c[wr] = make_float2(tc[wr], tc[wr + 2]);
            t2l[wr] = make_float2(tl[wr], tl[wr + 2]);
            t2r[wr] = make_float2(tr[wr], tr[wr + 2]);
        }

        // packed weights: 9 x ds_read_b128 broadcast; view as float2 pairs for op_sel
        float w[36];
        const float* pw = sw + ci * 36;
        #pragma unroll
        for (int u = 0; u < 9; ++u)
            *(float4*)&w[4 * u] = *(const float4*)&pw[4 * u];
        const float2* w2 = (const float2*)w;

        #pragma unroll
        for (int c = 0; c < CPT; ++c) {
            float2 r2 = make_float2(0.0f, 0.0f);
            #pragma unroll
            for (int k = 0; k < 9; ++k) {
                const int wr = k / 3;
                const int kj = k % 3;
                const float2 t2 = (kj == 0) ? t2l[wr] : ((kj == 1) ? t2c[wr] : t2r[wr]);
                const int ia = c * 9 + k;           // wA[k] at w2[ia/2][ia&1]
                const int ic = 18 + c * 9 + k;      // wC[k]
                // prod = t * y  (y broadcast from its pair half, compile-time)
                float2 prod = (ia & 1) ? pk_mul_sel<1>(t2, w2[ia / 2])
                                       : pk_mul_sel<0>(t2, w2[ia / 2]);
                // pixel parity == S -> step parity = S^(k&1); even: r=(r+t)*y = r*y+prod
                //                                             odd : r=(r+y)*t = r*t+prod
                if ((k & 1) == S)
                    r2 = (ia & 1) ? pk_fma_sel<1>(r2, w2[ia / 2], prod)
                                  : pk_fma_sel<0>(r2, w2[ia / 2], prod);
                else
                    r2 = pk_fma_(r2, t2, prod);
                cv2[c] = (ic & 1) ? pk_fma_sel<1>(t2, w2[ic / 2], cv2[c])
                                  : pk_fma_sel<0>(t2, w2[ic / 2], cv2[c]);
            }
            aeg2[c] = pk_add_(aeg2[c], r2);
        }
    }
}

__global__ __launch_bounds__(256, 4)
void aeg_conv_kernel(const float* __restrict__ x,
                     const float* __restrict__ weight,
                     const float* __restrict__ conv_w,
                     const float* __restrict__ conv_b,
                     float* __restrict__ out)
{
    __shared__ float sx[HR * G * ROWCI];          // 10*8*72*4 = 23040 B
    __shared__ float sw[CIN * 36];                // 32*36*4   = 4608 B

    const int tid = threadIdx.x;
    const int i0  = blockIdx.x * TH;
    const int n   = blockIdx.y;
    const int co0 = blockIdx.z * CPT;

    const int s  = (tid >> 6) & 1;      // wave parity class (wave-uniform)
    const int rg = tid >> 7;            // row group (0,1)
    const int h  = (tid >> 5) & 1;      // half-wave -> row offset
    const int m  = tid & 31;

    const int rb_local = rg * 4 + h;            // local first pixel row: {0,1,4,5}; owns +0,+2
    const int rb  = i0 + rb_local;              // absolute first pixel row
    const int cb  = (rb & 1) ^ s;               // column LSB for this lane's class
    const int col = 2 * m + cb;                 // owned column (both pixel rows)

    const float* xn = x + (size_t)n * (CIN * HH * WW);

    // ---- zero the halo-column slots (0 and 33) of every parity array, once ----
    for (int idx = tid; idx < HR * G * 2 * 2; idx += 256) {
        int arr  = idx >> 1;                    // 0..159
        int slot = (idx & 1) ? 33 : 0;
        sx[arr * 36 + slot] = 0.0f;
    }

    // ---- stage packed weight slice into LDS: [ci][A0|A1|C0|C1] ----
    for (int idx = tid; idx < CIN * 36; idx += 256) {
        int ci = idx / 36, slot = idx - ci * 36;
        int set = slot / 18, rem = slot - set * 18;
        int c2 = rem / 9, k = rem - c2 * 9;
        const float* src = set ? conv_w : weight;
        sw[idx] = src[((size_t)(co0 + c2) * CIN + ci) * 9 + k];
    }

    float2 aeg2[CPT], cv2[CPT];
    #pragma unroll
    for (int c = 0; c < CPT; ++c) {
        aeg2[c] = make_float2(0.0f, 0.0f);
        cv2[c]  = make_float2(0.0f, 0.0f);
    }

    for (int g = 0; g < CIN; g += G) {
        __syncthreads();                // previous readers done (also covers init writes)
        // ---- stage HR rows x G ci, parity-split: 5 iters of float4 + 4 b32 writes ----
        #pragma unroll
        for (int it = 0; it < 5; ++it) {
            int idx  = it * 256 + tid;          // 0..1279
            int f4   = idx & 15;                // 16B chunk within row
            int pair = idx >> 4;                // r10*G + cl, 0..79
            int r10  = pair >> 3;
            int cl   = pair & 7;
            int gi   = i0 - 1 + r10;
            float4 v = make_float4(0.f, 0.f, 0.f, 0.f);
            if ((unsigned)gi < (unsigned)HH)
                v = *(const float4*)&xn[(g + cl) * (HH * WW) + gi * WW + 4 * f4];
            int rp   = gi & 1;                  // parity array holding even cols
            float* base = &sx[pair * ROWCI];
            base[rp * 36 + 1 + 2 * f4]        = v.x;   // col 4f4
            base[rp * 36 + 2 + 2 * f4]        = v.z;   // col 4f4+2
            base[(rp ^ 1) * 36 + 1 + 2 * f4]  = v.y;   // col 4f4+1
            base[(rp ^ 1) * 36 + 2 + 2 * f4]  = v.w;   // col 4f4+3
        }
        __syncthreads();

        if (s == 0) math_g<0>(sx, sw, rb_local, m, cb, g, aeg2, cv2);
        else        math_g<1>(sx, sw, rb_local, m, cb, g, aeg2, cv2);
    }

    // ---- epilogue: sigmoid(aeg) * (conv + bias) ----
    #pragma unroll
    for (int p = 0; p < 2; ++p) {
        int i = rb + 2 * p;
        #pragma unroll
        for (int c = 0; c < CPT; ++c) {
            int co = co0 + c;
            float a = p ? aeg2[c].y : aeg2[c].x;
            float v = p ? cv2[c].y  : cv2[c].x;
            float conv = v + conv_b[co];
            float sg = 1.0f / (1.0f + __expf(-a));
            out[(((size_t)n * COUT + co) * HH + i) * WW + col] = sg * conv;
        }
    }
}

extern "C" void kernel_launch(void* const* d_in, const int* in_sizes, int n_in,
                              void* d_out, int out_size, void* d_ws, size_t ws_size,
                              hipStream_t stream) {
    const float* x      = (const float*)d_in[0];
    const float* weight = (const float*)d_in[1];
    const float* conv_w = (const float*)d_in[2];
    const float* conv_b = (const float*)d_in[3];
    float* out = (float*)d_out;

    dim3 grid(HH / TH, NB, COUT / CPT);   // 8 x 4 x 32 = 1024 blocks
    aeg_conv_kernel<<<grid, 256, 0, stream>>>(x, weight, conv_w, conv_b, out);
}